// Round 1
// baseline (432.452 us; speedup 1.0000x reference)
//
#include <hip/hip_runtime.h>

#define TPB 256

// ---------- kernel 1: per-block sums of n_sel = num_exec_acts[job_indices[j]] ----------
__global__ __launch_bounds__(TPB) void k_block_sums(const int* __restrict__ job_indices,
                                                    const int* __restrict__ num_exec_acts,
                                                    int J, int* __restrict__ bsum)
{
    __shared__ int sc[TPB];
    int j = blockIdx.x * TPB + threadIdx.x;
    int v = 0;
    if (j < J) v = num_exec_acts[job_indices[j]];
    sc[threadIdx.x] = v;
    __syncthreads();
    for (int d = TPB / 2; d > 0; d >>= 1) {
        if (threadIdx.x < d) sc[threadIdx.x] += sc[threadIdx.x + d];
        __syncthreads();
    }
    if (threadIdx.x == 0) bsum[blockIdx.x] = sc[0];
}

// ---------- kernel 2: exclusive scan of block sums (nb <= TPB; J=60000 -> nb=235) ----------
__global__ __launch_bounds__(TPB) void k_scan_bsums(const int* __restrict__ bsum, int nb,
                                                    int* __restrict__ boff)
{
    __shared__ int sc[TPB];
    int v = (threadIdx.x < nb) ? bsum[threadIdx.x] : 0;
    sc[threadIdx.x] = v;
    __syncthreads();
    for (int d = 1; d < TPB; d <<= 1) {
        int add = (threadIdx.x >= d) ? sc[threadIdx.x - d] : 0;
        __syncthreads();
        sc[threadIdx.x] += add;
        __syncthreads();
    }
    if (threadIdx.x < nb) boff[threadIdx.x] = sc[threadIdx.x] - v;  // exclusive
}

// ---------- kernel 3: scatter rpt[t] = j for each job's rows ----------
__global__ __launch_bounds__(TPB) void k_scatter_rpt(const int* __restrict__ job_indices,
                                                     const int* __restrict__ num_exec_acts,
                                                     const int* __restrict__ boff,
                                                     int J, int* __restrict__ rpt)
{
    __shared__ int sc[TPB];
    int j = blockIdx.x * TPB + threadIdx.x;
    int v = (j < J) ? num_exec_acts[job_indices[j]] : 0;
    sc[threadIdx.x] = v;
    __syncthreads();
    for (int d = 1; d < TPB; d <<= 1) {
        int add = (threadIdx.x >= d) ? sc[threadIdx.x - d] : 0;
        __syncthreads();
        sc[threadIdx.x] += add;
        __syncthreads();
    }
    int start = boff[blockIdx.x] + sc[threadIdx.x] - v;
    if (j < J) {
        for (int k = 0; k < v; k++) rpt[start + k] = j;
    }
}

// ---------- kernel 4: per-job h1_pre[j][o] = b1[o] + sum_{i<35} f_i * W1[i][o] (pre-relu) ----------
__global__ __launch_bounds__(TPB) void k_h1pre(const float* __restrict__ x,
                                               const float* __restrict__ h_dag,
                                               const float* __restrict__ h_glob,
                                               const int* __restrict__ ptr,
                                               const int* __restrict__ job_indices,
                                               const float* __restrict__ W1,
                                               const float* __restrict__ b1,
                                               int J, float* __restrict__ h1_pre)
{
    __shared__ float sW1[35 * 64];
    __shared__ float sb1[64];
    for (int i = threadIdx.x; i < 35 * 64; i += TPB) sW1[i] = W1[i];
    if (threadIdx.x < 64) sb1[threadIdx.x] = b1[threadIdx.x];
    __syncthreads();

    int j = blockIdx.x * TPB + threadIdx.x;
    if (j >= J) return;
    int ji   = job_indices[j];
    int node = ptr[ji];

    float f[35];
#pragma unroll
    for (int c = 0; c < 3; c++)  f[c]      = x[node * 5 + c];
#pragma unroll
    for (int c = 0; c < 16; c++) f[3 + c]  = h_dag[ji * 16 + c];
#pragma unroll
    for (int c = 0; c < 16; c++) f[19 + c] = h_glob[j * 16 + c];

    float acc[64];
#pragma unroll
    for (int o = 0; o < 64; o++) acc[o] = sb1[o];
#pragma unroll
    for (int i = 0; i < 35; i++) {
        float fi = f[i];
#pragma unroll
        for (int o = 0; o < 64; o++) acc[o] += fi * sW1[i * 64 + o];
    }

    float4* dst = (float4*)(h1_pre + (size_t)j * 64);
#pragma unroll
    for (int q = 0; q < 16; q++)
        dst[q] = make_float4(acc[4 * q], acc[4 * q + 1], acc[4 * q + 2], acc[4 * q + 3]);
}

// ---------- kernel 5: per-row MLP (layers 1-finish, 2, 3, 4), weights in LDS ----------
__global__ __launch_bounds__(TPB) void k_mlp(const float* __restrict__ h1_pre,
                                             const int* __restrict__ rpt,
                                             const int* __restrict__ exec_act_idx,
                                             const float* __restrict__ W1,
                                             const float* __restrict__ W2,
                                             const float* __restrict__ b2,
                                             const float* __restrict__ W3,
                                             const float* __restrict__ b3,
                                             const float* __restrict__ W4,
                                             const float* __restrict__ b4,
                                             float* __restrict__ out, int T)
{
    __shared__ float sW2[64 * 64];
    __shared__ float sW3[64 * 32];
    __shared__ float sW1r[64];
    __shared__ float sW4[32];
    __shared__ float sb2[64];
    __shared__ float sb3[32];
    __shared__ float sb4;

    for (int i = threadIdx.x; i < 64 * 64; i += TPB) sW2[i] = W2[i];
    for (int i = threadIdx.x; i < 64 * 32; i += TPB) sW3[i] = W3[i];
    if (threadIdx.x < 64) {
        sW1r[threadIdx.x] = W1[35 * 64 + threadIdx.x];
        sb2[threadIdx.x]  = b2[threadIdx.x];
    }
    if (threadIdx.x < 32) {
        sW4[threadIdx.x] = W4[threadIdx.x];
        sb3[threadIdx.x] = b3[threadIdx.x];
    }
    if (threadIdx.x == 0) sb4 = b4[0];
    __syncthreads();

    int t = blockIdx.x * TPB + threadIdx.x;
    if (t >= T) return;

    int   j  = rpt[t];
    float fe = (float)exec_act_idx[t] * (1.0f / 50.0f);

    float h1[64];
    const float4* hp = (const float4*)(h1_pre + (size_t)j * 64);
#pragma unroll
    for (int q = 0; q < 16; q++) {
        float4 v = hp[q];
        h1[4 * q]     = v.x;
        h1[4 * q + 1] = v.y;
        h1[4 * q + 2] = v.z;
        h1[4 * q + 3] = v.w;
    }
#pragma unroll
    for (int o = 0; o < 64; o++) h1[o] = fmaxf(h1[o] + fe * sW1r[o], 0.0f);

    float h2[64];
#pragma unroll
    for (int o = 0; o < 64; o++) h2[o] = sb2[o];
#pragma unroll
    for (int i = 0; i < 64; i++) {
        float a = h1[i];
#pragma unroll
        for (int o = 0; o < 64; o++) h2[o] += a * sW2[i * 64 + o];
    }
#pragma unroll
    for (int o = 0; o < 64; o++) h2[o] = fmaxf(h2[o], 0.0f);

    float h3[32];
#pragma unroll
    for (int o = 0; o < 32; o++) h3[o] = sb3[o];
#pragma unroll
    for (int i = 0; i < 64; i++) {
        float a = h2[i];
#pragma unroll
        for (int o = 0; o < 32; o++) h3[o] += a * sW3[i * 32 + o];
    }

    float acc = sb4;
#pragma unroll
    for (int i = 0; i < 32; i++) acc += fmaxf(h3[i], 0.0f) * sW4[i];

    out[t] = acc;
}

extern "C" void kernel_launch(void* const* d_in, const int* in_sizes, int n_in,
                              void* d_out, int out_size, void* d_ws, size_t ws_size,
                              hipStream_t stream)
{
    const float* x             = (const float*)d_in[0];
    const float* h_dag         = (const float*)d_in[1];
    const float* h_glob        = (const float*)d_in[2];
    const int*   ptr           = (const int*)d_in[3];
    const int*   job_indices   = (const int*)d_in[4];
    const int*   num_exec_acts = (const int*)d_in[5];
    const int*   exec_act_idx  = (const int*)d_in[6];
    const float* W1 = (const float*)d_in[7];
    const float* b1 = (const float*)d_in[8];
    const float* W2 = (const float*)d_in[9];
    const float* b2 = (const float*)d_in[10];
    const float* W3 = (const float*)d_in[11];
    const float* b3 = (const float*)d_in[12];
    const float* W4 = (const float*)d_in[13];
    const float* b4 = (const float*)d_in[14];
    float* out = (float*)d_out;

    int J = in_sizes[4];  // 60000
    int T = in_sizes[6];  // total ragged rows (== out_size)
    int nb = (J + TPB - 1) / TPB;

    // workspace layout (all recomputed every call; 0xAA poison is fine)
    char* wsp = (char*)d_ws;
    int* rpt = (int*)wsp;
    wsp += (((size_t)T * 4) + 255) / 256 * 256;
    int* bsum = (int*)wsp;
    wsp += (((size_t)nb * 4) + 255) / 256 * 256;
    int* boff = (int*)wsp;
    wsp += (((size_t)nb * 4) + 255) / 256 * 256;
    float* h1_pre = (float*)wsp;  // J*64 floats

    k_block_sums<<<nb, TPB, 0, stream>>>(job_indices, num_exec_acts, J, bsum);
    k_scan_bsums<<<1, TPB, 0, stream>>>(bsum, nb, boff);
    k_scatter_rpt<<<nb, TPB, 0, stream>>>(job_indices, num_exec_acts, boff, J, rpt);
    k_h1pre<<<nb, TPB, 0, stream>>>(x, h_dag, h_glob, ptr, job_indices, W1, b1, J, h1_pre);

    int nbT = (T + TPB - 1) / TPB;
    k_mlp<<<nbT, TPB, 0, stream>>>(h1_pre, rpt, exec_act_idx, W1, W2, b2, W3, b3, W4, b4, out, T);
}

// Round 2
// 376.771 us; speedup vs baseline: 1.1478x; 1.1478x over previous
//
#include <hip/hip_runtime.h>

#define TPB 256

// ---------- kernel 1: per-block sums of n_sel = num_exec_acts[job_indices[j]] ----------
__global__ __launch_bounds__(TPB) void k_block_sums(const int* __restrict__ job_indices,
                                                    const int* __restrict__ num_exec_acts,
                                                    int J, int* __restrict__ bsum)
{
    __shared__ int sc[TPB];
    int j = blockIdx.x * TPB + threadIdx.x;
    int v = 0;
    if (j < J) v = num_exec_acts[job_indices[j]];
    sc[threadIdx.x] = v;
    __syncthreads();
    for (int d = TPB / 2; d > 0; d >>= 1) {
        if (threadIdx.x < d) sc[threadIdx.x] += sc[threadIdx.x + d];
        __syncthreads();
    }
    if (threadIdx.x == 0) bsum[blockIdx.x] = sc[0];
}

// ---------- kernel 2: exclusive scan of block sums (nb <= TPB; J=60000 -> nb=235) ----------
__global__ __launch_bounds__(TPB) void k_scan_bsums(const int* __restrict__ bsum, int nb,
                                                    int* __restrict__ boff)
{
    __shared__ int sc[TPB];
    int v = (threadIdx.x < nb) ? bsum[threadIdx.x] : 0;
    sc[threadIdx.x] = v;
    __syncthreads();
    for (int d = 1; d < TPB; d <<= 1) {
        int add = (threadIdx.x >= d) ? sc[threadIdx.x - d] : 0;
        __syncthreads();
        sc[threadIdx.x] += add;
        __syncthreads();
    }
    if (threadIdx.x < nb) boff[threadIdx.x] = sc[threadIdx.x] - v;  // exclusive
}

// ---------- kernel 3: scatter rpt[t] = j for each job's rows ----------
__global__ __launch_bounds__(TPB) void k_scatter_rpt(const int* __restrict__ job_indices,
                                                     const int* __restrict__ num_exec_acts,
                                                     const int* __restrict__ boff,
                                                     int J, int* __restrict__ rpt)
{
    __shared__ int sc[TPB];
    int j = blockIdx.x * TPB + threadIdx.x;
    int v = (j < J) ? num_exec_acts[job_indices[j]] : 0;
    sc[threadIdx.x] = v;
    __syncthreads();
    for (int d = 1; d < TPB; d <<= 1) {
        int add = (threadIdx.x >= d) ? sc[threadIdx.x - d] : 0;
        __syncthreads();
        sc[threadIdx.x] += add;
        __syncthreads();
    }
    int start = boff[blockIdx.x] + sc[threadIdx.x] - v;
    if (j < J) {
        for (int k = 0; k < v; k++) rpt[start + k] = j;
    }
}

// ---------- kernel 4: per-job h1_pre (pre-relu), weights via scalar (uniform) loads ----------
__global__ __launch_bounds__(TPB) void k_h1pre(const float* __restrict__ x,
                                               const float* __restrict__ h_dag,
                                               const float* __restrict__ h_glob,
                                               const int* __restrict__ ptr,
                                               const int* __restrict__ job_indices,
                                               const float* __restrict__ W1,
                                               const float* __restrict__ b1,
                                               int J, float* __restrict__ h1_pre)
{
    int j = blockIdx.x * TPB + threadIdx.x;
    if (j >= J) return;
    int ji   = job_indices[j];
    int node = ptr[ji];

    float f[35];
#pragma unroll
    for (int c = 0; c < 3; c++)  f[c]      = x[node * 5 + c];
#pragma unroll
    for (int c = 0; c < 16; c++) f[3 + c]  = h_dag[ji * 16 + c];
#pragma unroll
    for (int c = 0; c < 16; c++) f[19 + c] = h_glob[j * 16 + c];

    float acc[64];
#pragma unroll
    for (int o = 0; o < 64; o++) acc[o] = b1[o];            // uniform -> s_load
#pragma unroll
    for (int i = 0; i < 35; i++) {
        float fi = f[i];
#pragma unroll
        for (int o = 0; o < 64; o++) acc[o] = fmaf(fi, W1[i * 64 + o], acc[o]);  // uniform W1
    }

    float4* dst = (float4*)(h1_pre + (size_t)j * 64);
#pragma unroll
    for (int q = 0; q < 16; q++)
        dst[q] = make_float4(acc[4 * q], acc[4 * q + 1], acc[4 * q + 2], acc[4 * q + 3]);
}

// ---------- kernel 5: per-row MLP; all weights via scalar (uniform) loads, no LDS ----------
__global__ __launch_bounds__(TPB) void k_mlp(const float* __restrict__ h1_pre,
                                             const int* __restrict__ rpt,
                                             const int* __restrict__ exec_act_idx,
                                             const float* __restrict__ W1,
                                             const float* __restrict__ W2,
                                             const float* __restrict__ b2,
                                             const float* __restrict__ W3,
                                             const float* __restrict__ b3,
                                             const float* __restrict__ W4,
                                             const float* __restrict__ b4,
                                             float* __restrict__ out, int T)
{
    int t = blockIdx.x * TPB + threadIdx.x;
    if (t >= T) return;

    int   j  = rpt[t];
    float fe = (float)exec_act_idx[t] * (1.0f / 50.0f);

    float h1[64];
    const float4* hp = (const float4*)(h1_pre + (size_t)j * 64);
#pragma unroll
    for (int q = 0; q < 16; q++) {
        float4 v = hp[q];
        h1[4 * q]     = v.x;
        h1[4 * q + 1] = v.y;
        h1[4 * q + 2] = v.z;
        h1[4 * q + 3] = v.w;
    }
#pragma unroll
    for (int o = 0; o < 64; o++)
        h1[o] = fmaxf(fmaf(fe, W1[35 * 64 + o], h1[o]), 0.0f);   // uniform last W1 row

    float h2[64];
#pragma unroll
    for (int o = 0; o < 64; o++) h2[o] = b2[o];
#pragma unroll
    for (int i = 0; i < 64; i++) {
        float a = h1[i];
#pragma unroll
        for (int o = 0; o < 64; o++) h2[o] = fmaf(a, W2[i * 64 + o], h2[o]);   // uniform W2
    }
#pragma unroll
    for (int o = 0; o < 64; o++) h2[o] = fmaxf(h2[o], 0.0f);

    float h3[32];
#pragma unroll
    for (int o = 0; o < 32; o++) h3[o] = b3[o];
#pragma unroll
    for (int i = 0; i < 64; i++) {
        float a = h2[i];
#pragma unroll
        for (int o = 0; o < 32; o++) h3[o] = fmaf(a, W3[i * 32 + o], h3[o]);   // uniform W3
    }

    float acc = b4[0];
#pragma unroll
    for (int i = 0; i < 32; i++) acc = fmaf(fmaxf(h3[i], 0.0f), W4[i], acc);   // uniform W4

    out[t] = acc;
}

extern "C" void kernel_launch(void* const* d_in, const int* in_sizes, int n_in,
                              void* d_out, int out_size, void* d_ws, size_t ws_size,
                              hipStream_t stream)
{
    const float* x             = (const float*)d_in[0];
    const float* h_dag         = (const float*)d_in[1];
    const float* h_glob        = (const float*)d_in[2];
    const int*   ptr           = (const int*)d_in[3];
    const int*   job_indices   = (const int*)d_in[4];
    const int*   num_exec_acts = (const int*)d_in[5];
    const int*   exec_act_idx  = (const int*)d_in[6];
    const float* W1 = (const float*)d_in[7];
    const float* b1 = (const float*)d_in[8];
    const float* W2 = (const float*)d_in[9];
    const float* b2 = (const float*)d_in[10];
    const float* W3 = (const float*)d_in[11];
    const float* b3 = (const float*)d_in[12];
    const float* W4 = (const float*)d_in[13];
    const float* b4 = (const float*)d_in[14];
    float* out = (float*)d_out;

    int J = in_sizes[4];  // 60000
    int T = in_sizes[6];  // total ragged rows (== out_size)
    int nb = (J + TPB - 1) / TPB;

    // workspace layout (recomputed every call; 0xAA poison is fine)
    char* wsp = (char*)d_ws;
    int* rpt = (int*)wsp;
    wsp += (((size_t)T * 4) + 255) / 256 * 256;
    int* bsum = (int*)wsp;
    wsp += (((size_t)nb * 4) + 255) / 256 * 256;
    int* boff = (int*)wsp;
    wsp += (((size_t)nb * 4) + 255) / 256 * 256;
    float* h1_pre = (float*)wsp;  // J*64 floats

    k_block_sums<<<nb, TPB, 0, stream>>>(job_indices, num_exec_acts, J, bsum);
    k_scan_bsums<<<1, TPB, 0, stream>>>(bsum, nb, boff);
    k_scatter_rpt<<<nb, TPB, 0, stream>>>(job_indices, num_exec_acts, boff, J, rpt);
    k_h1pre<<<nb, TPB, 0, stream>>>(x, h_dag, h_glob, ptr, job_indices, W1, b1, J, h1_pre);

    int nbT = (T + TPB - 1) / TPB;
    k_mlp<<<nbT, TPB, 0, stream>>>(h1_pre, rpt, exec_act_idx, W1, W2, b2, W3, b3, W4, b4, out, T);
}

// Round 3
// 261.334 us; speedup vs baseline: 1.6548x; 1.4417x over previous
//
#include <hip/hip_runtime.h>

#define TPB 256

using half8 = __attribute__((ext_vector_type(8))) _Float16;
using f32x4 = __attribute__((ext_vector_type(4))) float;

static __device__ __forceinline__ unsigned short h2u(_Float16 h) {
    union { _Float16 h; unsigned short u; } v; v.h = h; return v.u;
}

// ---------- kernel 1: per-block sums of n_sel ----------
__global__ __launch_bounds__(TPB) void k_block_sums(const int* __restrict__ job_indices,
                                                    const int* __restrict__ num_exec_acts,
                                                    int J, int* __restrict__ bsum)
{
    __shared__ int sc[TPB];
    int j = blockIdx.x * TPB + threadIdx.x;
    int v = 0;
    if (j < J) v = num_exec_acts[job_indices[j]];
    sc[threadIdx.x] = v;
    __syncthreads();
    for (int d = TPB / 2; d > 0; d >>= 1) {
        if (threadIdx.x < d) sc[threadIdx.x] += sc[threadIdx.x + d];
        __syncthreads();
    }
    if (threadIdx.x == 0) bsum[blockIdx.x] = sc[0];
}

// ---------- kernel 2: exclusive scan of block sums (nb <= TPB) ----------
__global__ __launch_bounds__(TPB) void k_scan_bsums(const int* __restrict__ bsum, int nb,
                                                    int* __restrict__ boff)
{
    __shared__ int sc[TPB];
    int v = (threadIdx.x < nb) ? bsum[threadIdx.x] : 0;
    sc[threadIdx.x] = v;
    __syncthreads();
    for (int d = 1; d < TPB; d <<= 1) {
        int add = (threadIdx.x >= d) ? sc[threadIdx.x - d] : 0;
        __syncthreads();
        sc[threadIdx.x] += add;
        __syncthreads();
    }
    if (threadIdx.x < nb) boff[threadIdx.x] = sc[threadIdx.x] - v;  // exclusive
}

// ---------- kernel 3: per-job ragged start offsets ----------
__global__ __launch_bounds__(TPB) void k_job_starts(const int* __restrict__ job_indices,
                                                    const int* __restrict__ num_exec_acts,
                                                    const int* __restrict__ boff,
                                                    int J, int* __restrict__ js)
{
    __shared__ int sc[TPB];
    int j = blockIdx.x * TPB + threadIdx.x;
    int v = (j < J) ? num_exec_acts[job_indices[j]] : 0;
    sc[threadIdx.x] = v;
    __syncthreads();
    for (int d = 1; d < TPB; d <<= 1) {
        int add = (threadIdx.x >= d) ? sc[threadIdx.x - d] : 0;
        __syncthreads();
        sc[threadIdx.x] += add;
        __syncthreads();
    }
    if (j < J) js[j] = boff[blockIdx.x] + sc[threadIdx.x] - v;
}

// ---------- kernel 4: fill rpt, one wave per job (n <= 50 < 64) ----------
__global__ __launch_bounds__(TPB) void k_fill_rpt(const int* __restrict__ job_indices,
                                                  const int* __restrict__ num_exec_acts,
                                                  const int* __restrict__ js,
                                                  int J, int* __restrict__ rpt)
{
    int wid = blockIdx.x * 4 + (threadIdx.x >> 6);
    if (wid >= J) return;
    int n = num_exec_acts[job_indices[wid]];
    int st = js[wid];
    int lane = threadIdx.x & 63;
    if (lane < n) rpt[st + lane] = wid;
}

// ---------- kernel 5: pack per-job features as fp16 (40 halves = 20 words/job) ----------
__global__ __launch_bounds__(TPB) void k_pack(const float* __restrict__ x,
                                              const float* __restrict__ h_dag,
                                              const float* __restrict__ h_glob,
                                              const int* __restrict__ ptr,
                                              const int* __restrict__ job_indices,
                                              int J, unsigned int* __restrict__ feat)
{
    int j = blockIdx.x * TPB + threadIdx.x;
    if (j >= J) return;
    int ji   = job_indices[j];
    int node = ptr[ji];
    float f[40];
    f[0] = x[node * 5 + 0];
    f[1] = x[node * 5 + 1];
    f[2] = x[node * 5 + 2];
#pragma unroll
    for (int c = 0; c < 16; c++) f[3 + c]  = h_dag[ji * 16 + c];
#pragma unroll
    for (int c = 0; c < 16; c++) f[19 + c] = h_glob[j * 16 + c];
#pragma unroll
    for (int c = 35; c < 40; c++) f[c] = 0.0f;
    unsigned int w[20];
#pragma unroll
    for (int k = 0; k < 20; k++)
        w[k] = (unsigned)h2u((_Float16)f[2 * k]) | ((unsigned)h2u((_Float16)f[2 * k + 1]) << 16);
    uint4* dst = (uint4*)(feat + (size_t)j * 20);
#pragma unroll
    for (int qq = 0; qq < 5; qq++)
        dst[qq] = make_uint4(w[4 * qq], w[4 * qq + 1], w[4 * qq + 2], w[4 * qq + 3]);
}

// ---------- kernel 6: fused MFMA MLP (128 rows/block) ----------
// LDS activation layout per layer: chunked fp16 [kchunk][row][8 halves], 16 B/row/chunk
// -> A-frag (m=lane&15, k=quad*8+j) is one ds_read_b128 at stride 16 B (conflict-free).
__global__ __launch_bounds__(TPB) void k_mlp_mfma(const unsigned int* __restrict__ feat,
                                                  const int* __restrict__ rpt,
                                                  const int* __restrict__ exec_act_idx,
                                                  const float* __restrict__ W1,
                                                  const float* __restrict__ b1,
                                                  const float* __restrict__ W2,
                                                  const float* __restrict__ b2,
                                                  const float* __restrict__ W3,
                                                  const float* __restrict__ b3,
                                                  const float* __restrict__ W4,
                                                  const float* __restrict__ b4,
                                                  float* __restrict__ out, int T)
{
    // slot0 (16384 B): A1, then reused as A3.  slot1 (16896 B): A2, then reused as h3f.
    __shared__ __align__(16) char smem[16384 + 16896];
    char* slot0 = smem;
    char* slot1 = smem + 16384;

    const int tid  = threadIdx.x;
    const int lane = tid & 63;
    const int wv   = tid >> 6;     // wave 0..3
    const int n    = lane & 15;
    const int q    = lane >> 4;
    const int base = blockIdx.x * 128;

    // ---- build A1: 64-half rows = 36 real feats (exec at 35) + zero pad ----
    {
        const int p = tid >> 7;    // 0: chunks 0-3, 1: chunk 4 + zero 5-7
        const int r = tid & 127;
        int  t     = base + r;
        bool valid = t < T;
        int  j     = valid ? rpt[t] : 0;
        const uint4* src = (const uint4*)(feat + (size_t)j * 20);
        if (p == 0) {
#pragma unroll
            for (int c = 0; c < 4; c++)
                *(uint4*)(slot0 + (c * 128 + r) * 16) = src[c];
        } else {
            uint4 v  = src[4];
            float fe = valid ? (float)exec_act_idx[t] * 0.02f : 0.0f;
            unsigned hu = h2u((_Float16)fe);
            v.y = (v.y & 0xffffu) | (hu << 16);   // half index 35 = high half of word 17
            *(uint4*)(slot0 + (4 * 128 + r) * 16) = v;
            uint4 z = make_uint4(0, 0, 0, 0);
#pragma unroll
            for (int c = 5; c < 8; c++)
                *(uint4*)(slot0 + (c * 128 + r) * 16) = z;
        }
    }

    // ---- B fragments (weights, K padded to 64) + bias fragments ----
    // B-frag layout: n = lane&15, k = quad*8 + j  (B[k][n], row-major W[k*N+n])
    half8 bw1[4][2], bw2[4][2], bw3[2][2];
    float bb1[4], bb2[4], bb3[2];
#pragma unroll
    for (int nt = 0; nt < 4; nt++) {
        bb1[nt] = b1[nt * 16 + n];
        bb2[nt] = b2[nt * 16 + n];
#pragma unroll
        for (int s = 0; s < 2; s++) {
#pragma unroll
            for (int jj = 0; jj < 8; jj++) {
                int ks = s * 32 + q * 8 + jj;
                bw1[nt][s][jj] = (ks < 36) ? (_Float16)W1[ks * 64 + nt * 16 + n] : (_Float16)0.0f;
                bw2[nt][s][jj] = (_Float16)W2[ks * 64 + nt * 16 + n];
            }
        }
    }
#pragma unroll
    for (int nt = 0; nt < 2; nt++) {
        bb3[nt] = b3[nt * 16 + n];
#pragma unroll
        for (int s = 0; s < 2; s++) {
#pragma unroll
            for (int jj = 0; jj < 8; jj++) {
                int ks = s * 32 + q * 8 + jj;
                bw3[nt][s][jj] = (_Float16)W3[ks * 32 + nt * 16 + n];
            }
        }
    }

    __syncthreads();

    const int R0 = 32 * wv;        // this wave's 32 rows (2 m-tiles)

    // ---- layer 1: A1(slot0) @ W1 -> relu -> A2(slot1) ----
#pragma unroll
    for (int mt = 0; mt < 2; mt++) {
        int M0 = R0 + 16 * mt;
        f32x4 acc[4];
#pragma unroll
        for (int nt = 0; nt < 4; nt++) { f32x4 c; c[0] = c[1] = c[2] = c[3] = bb1[nt]; acc[nt] = c; }
#pragma unroll
        for (int s = 0; s < 2; s++) {
            half8 a = *(const half8*)(slot0 + ((s * 4 + q) * 128 + (M0 + n)) * 16);
#pragma unroll
            for (int nt = 0; nt < 4; nt++)
                acc[nt] = __builtin_amdgcn_mfma_f32_16x16x32_f16(a, bw1[nt][s], acc[nt], 0, 0, 0);
        }
        _Float16* A2h = (_Float16*)slot1;
#pragma unroll
        for (int nt = 0; nt < 4; nt++) {
            int col = nt * 16 + n;
#pragma unroll
            for (int reg = 0; reg < 4; reg++) {
                int row = M0 + q * 4 + reg;
                A2h[(col >> 3) * 1024 + row * 8 + (col & 7)] = (_Float16)fmaxf(acc[nt][reg], 0.0f);
            }
        }
    }
    __syncthreads();

    // ---- layer 2: A2(slot1) @ W2 -> relu -> A3(slot0) ----
#pragma unroll
    for (int mt = 0; mt < 2; mt++) {
        int M0 = R0 + 16 * mt;
        f32x4 acc[4];
#pragma unroll
        for (int nt = 0; nt < 4; nt++) { f32x4 c; c[0] = c[1] = c[2] = c[3] = bb2[nt]; acc[nt] = c; }
#pragma unroll
        for (int s = 0; s < 2; s++) {
            half8 a = *(const half8*)(slot1 + ((s * 4 + q) * 128 + (M0 + n)) * 16);
#pragma unroll
            for (int nt = 0; nt < 4; nt++)
                acc[nt] = __builtin_amdgcn_mfma_f32_16x16x32_f16(a, bw2[nt][s], acc[nt], 0, 0, 0);
        }
        _Float16* A3h = (_Float16*)slot0;
#pragma unroll
        for (int nt = 0; nt < 4; nt++) {
            int col = nt * 16 + n;
#pragma unroll
            for (int reg = 0; reg < 4; reg++) {
                int row = M0 + q * 4 + reg;
                A3h[(col >> 3) * 1024 + row * 8 + (col & 7)] = (_Float16)fmaxf(acc[nt][reg], 0.0f);
            }
        }
    }
    __syncthreads();

    // ---- layer 3: A3(slot0) @ W3 -> relu -> h3f(slot1, fp32 [128][33]) ----
    float* h3f = (float*)slot1;
#pragma unroll
    for (int mt = 0; mt < 2; mt++) {
        int M0 = R0 + 16 * mt;
        f32x4 acc[2];
#pragma unroll
        for (int nt = 0; nt < 2; nt++) { f32x4 c; c[0] = c[1] = c[2] = c[3] = bb3[nt]; acc[nt] = c; }
#pragma unroll
        for (int s = 0; s < 2; s++) {
            half8 a = *(const half8*)(slot0 + ((s * 4 + q) * 128 + (M0 + n)) * 16);
#pragma unroll
            for (int nt = 0; nt < 2; nt++)
                acc[nt] = __builtin_amdgcn_mfma_f32_16x16x32_f16(a, bw3[nt][s], acc[nt], 0, 0, 0);
        }
#pragma unroll
        for (int nt = 0; nt < 2; nt++) {
            int col = nt * 16 + n;
#pragma unroll
            for (int reg = 0; reg < 4; reg++) {
                int row = M0 + q * 4 + reg;
                h3f[row * 33 + col] = fmaxf(acc[nt][reg], 0.0f);
            }
        }
    }
    __syncthreads();

    // ---- layer 4: per-row dot(relu(h3), W4) + b4 ----
    if (tid < 128) {
        int t = base + tid;
        if (t < T) {
            float acc = b4[0];
#pragma unroll
            for (int i = 0; i < 32; i++) acc = fmaf(h3f[tid * 33 + i], W4[i], acc);
            out[t] = acc;
        }
    }
}

extern "C" void kernel_launch(void* const* d_in, const int* in_sizes, int n_in,
                              void* d_out, int out_size, void* d_ws, size_t ws_size,
                              hipStream_t stream)
{
    const float* x             = (const float*)d_in[0];
    const float* h_dag         = (const float*)d_in[1];
    const float* h_glob        = (const float*)d_in[2];
    const int*   ptr           = (const int*)d_in[3];
    const int*   job_indices   = (const int*)d_in[4];
    const int*   num_exec_acts = (const int*)d_in[5];
    const int*   exec_act_idx  = (const int*)d_in[6];
    const float* W1 = (const float*)d_in[7];
    const float* b1 = (const float*)d_in[8];
    const float* W2 = (const float*)d_in[9];
    const float* b2 = (const float*)d_in[10];
    const float* W3 = (const float*)d_in[11];
    const float* b3 = (const float*)d_in[12];
    const float* W4 = (const float*)d_in[13];
    const float* b4 = (const float*)d_in[14];
    float* out = (float*)d_out;

    int J  = in_sizes[4];
    int T  = in_sizes[6];
    int nb = (J + TPB - 1) / TPB;

    // workspace layout
    char* wsp = (char*)d_ws;
    int* rpt = (int*)wsp;
    wsp += (((size_t)T * 4) + 255) / 256 * 256;
    int* bsum = (int*)wsp;
    wsp += (((size_t)nb * 4) + 255) / 256 * 256;
    int* boff = (int*)wsp;
    wsp += (((size_t)nb * 4) + 255) / 256 * 256;
    int* js = (int*)wsp;
    wsp += (((size_t)J * 4) + 255) / 256 * 256;
    unsigned int* feat = (unsigned int*)wsp;   // J*20 words

    k_block_sums<<<nb, TPB, 0, stream>>>(job_indices, num_exec_acts, J, bsum);
    k_scan_bsums<<<1, TPB, 0, stream>>>(bsum, nb, boff);
    k_job_starts<<<nb, TPB, 0, stream>>>(job_indices, num_exec_acts, boff, J, js);
    k_fill_rpt<<<(J + 3) / 4, TPB, 0, stream>>>(job_indices, num_exec_acts, js, J, rpt);
    k_pack<<<nb, TPB, 0, stream>>>(x, h_dag, h_glob, ptr, job_indices, J, feat);

    int nbT = (T + 127) / 128;
    k_mlp_mfma<<<nbT, TPB, 0, stream>>>(feat, rpt, exec_act_idx,
                                        W1, b1, W2, b2, W3, b3, W4, b4, out, T);
}

// Round 4
// 214.110 us; speedup vs baseline: 2.0198x; 1.2206x over previous
//
#include <hip/hip_runtime.h>

#define TPB 256

using half8 = __attribute__((ext_vector_type(8))) _Float16;
using f32x4 = __attribute__((ext_vector_type(4))) float;

static __device__ __forceinline__ unsigned short h2u(_Float16 h) {
    union { _Float16 h; unsigned short u; } v; v.h = h; return v.u;
}

// ---------- kernel 1: pack per-job fp16 features (40 halves) + per-block sums of n_sel ----------
__global__ __launch_bounds__(TPB) void k_prep(const float* __restrict__ x,
                                              const float* __restrict__ h_dag,
                                              const float* __restrict__ h_glob,
                                              const int* __restrict__ ptr,
                                              const int* __restrict__ job_indices,
                                              const int* __restrict__ num_exec_acts,
                                              int J, unsigned int* __restrict__ feat,
                                              int* __restrict__ bsum)
{
    __shared__ int sc[TPB];
    int j = blockIdx.x * TPB + threadIdx.x;
    int v = 0;
    if (j < J) {
        int ji   = job_indices[j];
        v        = num_exec_acts[ji];
        int node = ptr[ji];
        float f[40];
        f[0] = x[node * 5 + 0];
        f[1] = x[node * 5 + 1];
        f[2] = x[node * 5 + 2];
#pragma unroll
        for (int c = 0; c < 16; c++) f[3 + c]  = h_dag[ji * 16 + c];
#pragma unroll
        for (int c = 0; c < 16; c++) f[19 + c] = h_glob[j * 16 + c];
#pragma unroll
        for (int c = 35; c < 40; c++) f[c] = 0.0f;
        unsigned int w[20];
#pragma unroll
        for (int k = 0; k < 20; k++)
            w[k] = (unsigned)h2u((_Float16)f[2 * k]) | ((unsigned)h2u((_Float16)f[2 * k + 1]) << 16);
        uint4* dst = (uint4*)(feat + (size_t)j * 20);
#pragma unroll
        for (int qq = 0; qq < 5; qq++)
            dst[qq] = make_uint4(w[4 * qq], w[4 * qq + 1], w[4 * qq + 2], w[4 * qq + 3]);
    }
    sc[threadIdx.x] = v;
    __syncthreads();
    for (int d = TPB / 2; d > 0; d >>= 1) {
        if (threadIdx.x < d) sc[threadIdx.x] += sc[threadIdx.x + d];
        __syncthreads();
    }
    if (threadIdx.x == 0) bsum[blockIdx.x] = sc[0];
}

// ---------- kernel 2: exclusive scan of block sums (nb <= TPB) ----------
__global__ __launch_bounds__(TPB) void k_scan_bsums(const int* __restrict__ bsum, int nb,
                                                    int* __restrict__ boff)
{
    __shared__ int sc[TPB];
    int v = (threadIdx.x < nb) ? bsum[threadIdx.x] : 0;
    sc[threadIdx.x] = v;
    __syncthreads();
    for (int d = 1; d < TPB; d <<= 1) {
        int add = (threadIdx.x >= d) ? sc[threadIdx.x - d] : 0;
        __syncthreads();
        sc[threadIdx.x] += add;
        __syncthreads();
    }
    if (threadIdx.x < nb) boff[threadIdx.x] = sc[threadIdx.x] - v;  // exclusive
}

// ---------- kernel 3: per-job ragged start offsets ----------
__global__ __launch_bounds__(TPB) void k_job_starts(const int* __restrict__ job_indices,
                                                    const int* __restrict__ num_exec_acts,
                                                    const int* __restrict__ boff,
                                                    int J, int* __restrict__ js)
{
    __shared__ int sc[TPB];
    int j = blockIdx.x * TPB + threadIdx.x;
    int v = (j < J) ? num_exec_acts[job_indices[j]] : 0;
    sc[threadIdx.x] = v;
    __syncthreads();
    for (int d = 1; d < TPB; d <<= 1) {
        int add = (threadIdx.x >= d) ? sc[threadIdx.x - d] : 0;
        __syncthreads();
        sc[threadIdx.x] += add;
        __syncthreads();
    }
    if (j < J) js[j] = boff[blockIdx.x] + sc[threadIdx.x] - v;
}

// ---------- kernel 4: fill rpt, one wave per job (n <= 50 < 64) ----------
__global__ __launch_bounds__(TPB) void k_fill_rpt(const int* __restrict__ job_indices,
                                                  const int* __restrict__ num_exec_acts,
                                                  const int* __restrict__ js,
                                                  int J, int* __restrict__ rpt)
{
    int wid = blockIdx.x * 4 + (threadIdx.x >> 6);
    if (wid >= J) return;
    int n = num_exec_acts[job_indices[wid]];
    int st = js[wid];
    int lane = threadIdx.x & 63;
    if (lane < n) rpt[st + lane] = wid;
}

// ---------- kernel 5: fused MFMA MLP, wave-private 32-row tiles, no barriers ----------
// LDS granule layout per wave slab: granule(row,c) holds halves A[row][8c..8c+7],
// at physical index P = row*8 + (c ^ ((row>>1)&7))  (16 B each; 4 KB per 32-row slab).
// Reads (lane n,q; chunk s*4+q; row M0+n): even 8-granules-per-bank-group.
// Writes (row=M0+4q+reg, c=2nt+(n>>3)): 8 granules -> 8 distinct bank groups (q enters via row>>1).
__global__ __launch_bounds__(TPB) void k_mlp_mfma(const unsigned int* __restrict__ feat,
                                                  const int* __restrict__ rpt,
                                                  const int* __restrict__ exec_act_idx,
                                                  const float* __restrict__ W1,
                                                  const float* __restrict__ b1,
                                                  const float* __restrict__ W2,
                                                  const float* __restrict__ b2,
                                                  const float* __restrict__ W3,
                                                  const float* __restrict__ b3,
                                                  const float* __restrict__ W4,
                                                  const float* __restrict__ b4,
                                                  float* __restrict__ out, int T, int numTiles)
{
    __shared__ __align__(16) char smem[4 * 8192];
    const int tid  = threadIdx.x;
    const int lane = tid & 63;
    const int wv   = tid >> 6;
    const int n    = lane & 15;
    const int q    = lane >> 4;
    char* slab0 = smem + wv * 8192;        // A1 / A3
    char* slab1 = slab0 + 4096;            // A2

    // ---- B fragments (per-block, loaded once): n = lane&15, k = q*8+jj, W[k*N+n] ----
    half8 bw1[4][2], bw2[4][2], bw3[2][2];
    float bb1[4], bb2[4], bb3[2];
#pragma unroll
    for (int nt = 0; nt < 4; nt++) {
        bb1[nt] = b1[nt * 16 + n];
        bb2[nt] = b2[nt * 16 + n];
#pragma unroll
        for (int s = 0; s < 2; s++) {
#pragma unroll
            for (int jj = 0; jj < 8; jj++) {
                int ks = s * 32 + q * 8 + jj;
                bw1[nt][s][jj] = (ks < 36) ? (_Float16)W1[ks * 64 + nt * 16 + n] : (_Float16)0.0f;
                bw2[nt][s][jj] = (_Float16)W2[ks * 64 + nt * 16 + n];
            }
        }
    }
#pragma unroll
    for (int nt = 0; nt < 2; nt++) {
        bb3[nt] = b3[nt * 16 + n];
#pragma unroll
        for (int s = 0; s < 2; s++) {
#pragma unroll
            for (int jj = 0; jj < 8; jj++) {
                int ks = s * 32 + q * 8 + jj;
                bw3[nt][s][jj] = (_Float16)W3[ks * 32 + nt * 16 + n];
            }
        }
    }
    const float w4a = W4[n];
    const float w4b = W4[16 + n];
    const float b4v = b4[0];
    const int   sw  = (n >> 1) & 7;   // read swizzle; same for M0=0 and M0=16

    for (int tile = blockIdx.x; tile < numTiles; tile += gridDim.x) {
        const int rowbase = tile * 128 + wv * 32;

        // ---- build A1 (32 rows x 64 halves; halves 36..63 zero; exec feat at 35) ----
#pragma unroll
        for (int it = 0; it < 4; it++) {
            int idx = it * 64 + lane;              // 0..255 = 32 rows x 8 granules
            int r = idx >> 3, c = idx & 7;
            int t = rowbase + r;
            uint4 v = make_uint4(0, 0, 0, 0);
            if (c < 5) {
                int j = (t < T) ? rpt[t] : 0;
                v = ((const uint4*)(feat + (size_t)j * 20))[c];
                if (c == 4) {
                    float fe = (t < T) ? (float)exec_act_idx[t] * 0.02f : 0.0f;
                    v.y = (v.y & 0xffffu) | ((unsigned)h2u((_Float16)fe) << 16);
                }
            }
            int P = r * 8 + (c ^ ((r >> 1) & 7));
            *(uint4*)(slab0 + P * 16) = v;
        }

        // ---- layer 1: A1(slab0) @ W1 + b1 -> relu -> A2(slab1) ----
#pragma unroll
        for (int mt = 0; mt < 2; mt++) {
            const int M0 = 16 * mt;
            f32x4 acc[4];
#pragma unroll
            for (int nt = 0; nt < 4; nt++) { f32x4 c; c[0]=c[1]=c[2]=c[3]=bb1[nt]; acc[nt]=c; }
#pragma unroll
            for (int s = 0; s < 2; s++) {
                half8 a = *(const half8*)(slab0 + ((M0 + n) * 8 + ((s * 4 + q) ^ sw)) * 16);
#pragma unroll
                for (int nt = 0; nt < 4; nt++)
                    acc[nt] = __builtin_amdgcn_mfma_f32_16x16x32_f16(a, bw1[nt][s], acc[nt], 0, 0, 0);
            }
#pragma unroll
            for (int nt = 0; nt < 4; nt++) {
                int cc = nt * 2 + (n >> 3);
#pragma unroll
                for (int reg = 0; reg < 4; reg++) {
                    int row = M0 + q * 4 + reg;
                    int P = row * 8 + (cc ^ ((row >> 1) & 7));
                    ((_Float16*)slab1)[P * 8 + (n & 7)] = (_Float16)fmaxf(acc[nt][reg], 0.0f);
                }
            }
        }

        // ---- layer 2: A2(slab1) @ W2 + b2 -> relu -> A3(slab0) ----
#pragma unroll
        for (int mt = 0; mt < 2; mt++) {
            const int M0 = 16 * mt;
            f32x4 acc[4];
#pragma unroll
            for (int nt = 0; nt < 4; nt++) { f32x4 c; c[0]=c[1]=c[2]=c[3]=bb2[nt]; acc[nt]=c; }
#pragma unroll
            for (int s = 0; s < 2; s++) {
                half8 a = *(const half8*)(slab1 + ((M0 + n) * 8 + ((s * 4 + q) ^ sw)) * 16);
#pragma unroll
                for (int nt = 0; nt < 4; nt++)
                    acc[nt] = __builtin_amdgcn_mfma_f32_16x16x32_f16(a, bw2[nt][s], acc[nt], 0, 0, 0);
            }
#pragma unroll
            for (int nt = 0; nt < 4; nt++) {
                int cc = nt * 2 + (n >> 3);
#pragma unroll
                for (int reg = 0; reg < 4; reg++) {
                    int row = M0 + q * 4 + reg;
                    int P = row * 8 + (cc ^ ((row >> 1) & 7));
                    ((_Float16*)slab0)[P * 8 + (n & 7)] = (_Float16)fmaxf(acc[nt][reg], 0.0f);
                }
            }
        }

        // ---- layer 3 + 4: A3(slab0) @ W3 + b3 -> relu -> dot W4 (+b4) via shuffle reduce ----
#pragma unroll
        for (int mt = 0; mt < 2; mt++) {
            const int M0 = 16 * mt;
            f32x4 acc[2];
#pragma unroll
            for (int nt = 0; nt < 2; nt++) { f32x4 c; c[0]=c[1]=c[2]=c[3]=bb3[nt]; acc[nt]=c; }
#pragma unroll
            for (int s = 0; s < 2; s++) {
                half8 a = *(const half8*)(slab0 + ((M0 + n) * 8 + ((s * 4 + q) ^ sw)) * 16);
#pragma unroll
                for (int nt = 0; nt < 2; nt++)
                    acc[nt] = __builtin_amdgcn_mfma_f32_16x16x32_f16(a, bw3[nt][s], acc[nt], 0, 0, 0);
            }
            f32x4 red;
#pragma unroll
            for (int reg = 0; reg < 4; reg++)
                red[reg] = fmaxf(acc[0][reg], 0.0f) * w4a + fmaxf(acc[1][reg], 0.0f) * w4b;
#pragma unroll
            for (int mask = 1; mask < 16; mask <<= 1) {
#pragma unroll
                for (int reg = 0; reg < 4; reg++)
                    red[reg] += __shfl_xor(red[reg], mask, 16);
            }
            int t = rowbase + M0 + q * 4 + n;     // n acts as reg selector for n<4
            float val = (n == 0) ? red[0] : (n == 1) ? red[1] : (n == 2) ? red[2] : red[3];
            if (n < 4 && t < T) out[t] = val + b4v;
        }
    }
}

extern "C" void kernel_launch(void* const* d_in, const int* in_sizes, int n_in,
                              void* d_out, int out_size, void* d_ws, size_t ws_size,
                              hipStream_t stream)
{
    const float* x             = (const float*)d_in[0];
    const float* h_dag         = (const float*)d_in[1];
    const float* h_glob        = (const float*)d_in[2];
    const int*   ptr           = (const int*)d_in[3];
    const int*   job_indices   = (const int*)d_in[4];
    const int*   num_exec_acts = (const int*)d_in[5];
    const int*   exec_act_idx  = (const int*)d_in[6];
    const float* W1 = (const float*)d_in[7];
    const float* b1 = (const float*)d_in[8];
    const float* W2 = (const float*)d_in[9];
    const float* b2 = (const float*)d_in[10];
    const float* W3 = (const float*)d_in[11];
    const float* b3 = (const float*)d_in[12];
    const float* W4 = (const float*)d_in[13];
    const float* b4 = (const float*)d_in[14];
    float* out = (float*)d_out;

    int J  = in_sizes[4];
    int T  = in_sizes[6];
    int nb = (J + TPB - 1) / TPB;

    // workspace layout
    char* wsp = (char*)d_ws;
    int* rpt = (int*)wsp;
    wsp += (((size_t)T * 4) + 255) / 256 * 256;
    int* bsum = (int*)wsp;
    wsp += (((size_t)nb * 4) + 255) / 256 * 256;
    int* boff = (int*)wsp;
    wsp += (((size_t)nb * 4) + 255) / 256 * 256;
    int* js = (int*)wsp;
    wsp += (((size_t)J * 4) + 255) / 256 * 256;
    unsigned int* feat = (unsigned int*)wsp;   // J*20 words

    k_prep<<<nb, TPB, 0, stream>>>(x, h_dag, h_glob, ptr, job_indices, num_exec_acts, J, feat, bsum);
    k_scan_bsums<<<1, TPB, 0, stream>>>(bsum, nb, boff);
    k_job_starts<<<nb, TPB, 0, stream>>>(job_indices, num_exec_acts, boff, J, js);
    k_fill_rpt<<<(J + 3) / 4, TPB, 0, stream>>>(job_indices, num_exec_acts, js, J, rpt);

    int numTiles = (T + 127) / 128;
    int grid = numTiles < 1024 ? numTiles : 1024;
    k_mlp_mfma<<<grid, TPB, 0, stream>>>(feat, rpt, exec_act_idx,
                                         W1, b1, W2, b2, W3, b3, W4, b4, out, T, numTiles);
}

// Round 6
// 183.993 us; speedup vs baseline: 2.3504x; 1.1637x over previous
//
#include <hip/hip_runtime.h>

#define TPB 256

using half8  = __attribute__((ext_vector_type(8))) _Float16;
using fp16x2 = __attribute__((ext_vector_type(2))) __fp16;
using f32x4  = __attribute__((ext_vector_type(4))) float;

static __device__ __forceinline__ unsigned short h2u(_Float16 h) {
    union { _Float16 h; unsigned short u; } v; v.h = h; return v.u;
}
static __device__ __forceinline__ unsigned pkrtz(float a, float b) {
    fp16x2 h = __builtin_amdgcn_cvt_pkrtz(a, b);
    return __builtin_bit_cast(unsigned, h);
}
template <int CTRL>
static __device__ __forceinline__ float dppmov(float x) {
    return __int_as_float(__builtin_amdgcn_mov_dpp(__float_as_int(x), CTRL, 0xF, 0xF, true));
}
// quad_perm [1,0,3,2] = swap adjacent lanes
#define DPP_SWAP 0xB1

// ---------- kernel 1: pack per-job fp16 features (40 halves) + per-block sums of n_sel ----------
__global__ __launch_bounds__(TPB) void k_prep(const float* __restrict__ x,
                                              const float* __restrict__ h_dag,
                                              const float* __restrict__ h_glob,
                                              const int* __restrict__ ptr,
                                              const int* __restrict__ job_indices,
                                              const int* __restrict__ num_exec_acts,
                                              int J, unsigned int* __restrict__ feat,
                                              int* __restrict__ bsum)
{
    __shared__ int sc[TPB];
    int j = blockIdx.x * TPB + threadIdx.x;
    int v = 0;
    if (j < J) {
        int ji   = job_indices[j];
        v        = num_exec_acts[ji];
        int node = ptr[ji];
        float f[40];
        f[0] = x[node * 5 + 0];
        f[1] = x[node * 5 + 1];
        f[2] = x[node * 5 + 2];
#pragma unroll
        for (int c = 0; c < 16; c++) f[3 + c]  = h_dag[ji * 16 + c];
#pragma unroll
        for (int c = 0; c < 16; c++) f[19 + c] = h_glob[j * 16 + c];
#pragma unroll
        for (int c = 35; c < 40; c++) f[c] = 0.0f;
        unsigned int w[20];
#pragma unroll
        for (int k = 0; k < 20; k++)
            w[k] = (unsigned)h2u((_Float16)f[2 * k]) | ((unsigned)h2u((_Float16)f[2 * k + 1]) << 16);
        uint4* dst = (uint4*)(feat + (size_t)j * 20);
#pragma unroll
        for (int qq = 0; qq < 5; qq++)
            dst[qq] = make_uint4(w[4 * qq], w[4 * qq + 1], w[4 * qq + 2], w[4 * qq + 3]);
    }
    sc[threadIdx.x] = v;
    __syncthreads();
    for (int d = TPB / 2; d > 0; d >>= 1) {
        if (threadIdx.x < d) sc[threadIdx.x] += sc[threadIdx.x + d];
        __syncthreads();
    }
    if (threadIdx.x == 0) bsum[blockIdx.x] = sc[0];
}

// ---------- kernel 2: exclusive scan of block sums (nb <= TPB) ----------
__global__ __launch_bounds__(TPB) void k_scan_bsums(const int* __restrict__ bsum, int nb,
                                                    int* __restrict__ boff)
{
    __shared__ int sc[TPB];
    int v = (threadIdx.x < nb) ? bsum[threadIdx.x] : 0;
    sc[threadIdx.x] = v;
    __syncthreads();
    for (int d = 1; d < TPB; d <<= 1) {
        int add = (threadIdx.x >= d) ? sc[threadIdx.x - d] : 0;
        __syncthreads();
        sc[threadIdx.x] += add;
        __syncthreads();
    }
    if (threadIdx.x < nb) boff[threadIdx.x] = sc[threadIdx.x] - v;  // exclusive
}

// ---------- kernel 3: block scan -> per-thread serial rpt fill ----------
__global__ __launch_bounds__(TPB) void k_starts_fill(const int* __restrict__ job_indices,
                                                     const int* __restrict__ num_exec_acts,
                                                     const int* __restrict__ boff,
                                                     int J, int* __restrict__ rpt)
{
    __shared__ int sc[TPB];
    int j = blockIdx.x * TPB + threadIdx.x;
    int v = (j < J) ? num_exec_acts[job_indices[j]] : 0;
    sc[threadIdx.x] = v;
    __syncthreads();
    for (int d = 1; d < TPB; d <<= 1) {
        int add = (threadIdx.x >= d) ? sc[threadIdx.x - d] : 0;
        __syncthreads();
        sc[threadIdx.x] += add;
        __syncthreads();
    }
    int start = boff[blockIdx.x] + sc[threadIdx.x] - v;
    if (j < J) {
        for (int k = 0; k < v; k++) rpt[start + k] = j;
    }
}

// ---------- kernel 4: fused MFMA MLP, wave-private 32-row tiles ----------
// A1 fragments loaded DIRECTLY from global (granule = A-frag). Inter-layer
// activations in wave-private LDS slabs, granule-swizzled:
//   granule(row,c) = halves A[row][8c..8c+7] at P = row*8 + (c ^ ((row>>1)&7)).
// Epilogue: DPP neighbor-swap + cvt_pkrtz -> 2 ds_write_b32 per lane per (mt,nt).
// L4: DPP row_ror reduction (no LDS).
__global__ __launch_bounds__(TPB) void k_mlp_mfma(const unsigned int* __restrict__ feat,
                                                  const int* __restrict__ rpt,
                                                  const int* __restrict__ exec_act_idx,
                                                  const float* __restrict__ W1,
                                                  const float* __restrict__ b1,
                                                  const float* __restrict__ W2,
                                                  const float* __restrict__ b2,
                                                  const float* __restrict__ W3,
                                                  const float* __restrict__ b3,
                                                  const float* __restrict__ W4,
                                                  const float* __restrict__ b4,
                                                  float* __restrict__ out, int T, int numTiles)
{
    __shared__ __align__(16) char smem[4 * 8192];
    const int tid  = threadIdx.x;
    const int lane = tid & 63;
    const int wv   = tid >> 6;
    const int n    = lane & 15;
    const int q    = lane >> 4;
    char* slab0 = smem + wv * 8192;        // A2
    char* slab1 = slab0 + 4096;            // A3

    // ---- B fragments (weights): n = lane&15, k = q*8+jj, W[k*N+n] ----
    half8 bw1[4][2], bw2[4][2], bw3[2][2];
    float bb1[4], bb2[4], bb3[2];
#pragma unroll
    for (int nt = 0; nt < 4; nt++) {
        bb1[nt] = b1[nt * 16 + n];
        bb2[nt] = b2[nt * 16 + n];
#pragma unroll
        for (int s = 0; s < 2; s++) {
#pragma unroll
            for (int jj = 0; jj < 8; jj++) {
                int ks = s * 32 + q * 8 + jj;
                bw1[nt][s][jj] = (ks < 36) ? (_Float16)W1[ks * 64 + nt * 16 + n] : (_Float16)0.0f;
                bw2[nt][s][jj] = (_Float16)W2[ks * 64 + nt * 16 + n];
            }
        }
    }
#pragma unroll
    for (int nt = 0; nt < 2; nt++) {
        bb3[nt] = b3[nt * 16 + n];
#pragma unroll
        for (int s = 0; s < 2; s++) {
#pragma unroll
            for (int jj = 0; jj < 8; jj++) {
                int ks = s * 32 + q * 8 + jj;
                bw3[nt][s][jj] = (_Float16)W3[ks * 32 + nt * 16 + n];
            }
        }
    }
    const float w4a = W4[n];
    const float w4b = W4[16 + n];
    const float b4v = b4[0];
    const int   swr = (n >> 1) & 7;       // read swizzle (M0-independent)
    const int   odd = n & 1;

    for (int tile = blockIdx.x; tile < numTiles; tile += gridDim.x) {
        const int rowbase = tile * 128 + wv * 32;

        // ---- A1 fragments straight from global ----
        half8 a1[2][2];
#pragma unroll
        for (int mt = 0; mt < 2; mt++) {
            int  rt    = rowbase + 16 * mt + n;
            bool valid = rt < T;
            int  j     = valid ? rpt[rt] : 0;
            const uint4* fsrc = (const uint4*)(feat + (size_t)j * 20);
            uint4 g0 = fsrc[q];                       // granule q: halves 8q..8q+7
            a1[mt][0] = __builtin_bit_cast(half8, g0);
            uint4 g1 = make_uint4(0, 0, 0, 0);
            if (q == 0) {                             // granule 4: halves 32..39, exec at 35
                g1 = fsrc[4];
                float fe = valid ? (float)exec_act_idx[rt] * 0.02f : 0.0f;
                g1.y = (g1.y & 0xffffu) | ((unsigned)h2u((_Float16)fe) << 16);
            }
            a1[mt][1] = __builtin_bit_cast(half8, g1);
        }

        // ---- layer 1 -> slab0 ----
#pragma unroll
        for (int mt = 0; mt < 2; mt++) {
            f32x4 acc[4];
#pragma unroll
            for (int nt = 0; nt < 4; nt++) { f32x4 c; c[0]=c[1]=c[2]=c[3]=bb1[nt]; acc[nt]=c; }
#pragma unroll
            for (int s = 0; s < 2; s++) {
#pragma unroll
                for (int nt = 0; nt < 4; nt++)
                    acc[nt] = __builtin_amdgcn_mfma_f32_16x16x32_f16(a1[mt][s], bw1[nt][s], acc[nt], 0, 0, 0);
            }
            unsigned* sl = (unsigned*)slab0;
#pragma unroll
            for (int nt = 0; nt < 4; nt++) {
                float v0 = fmaxf(acc[nt][0], 0.0f), v1 = fmaxf(acc[nt][1], 0.0f);
                float v2 = fmaxf(acc[nt][2], 0.0f), v3 = fmaxf(acc[nt][3], 0.0f);
                float t0 = dppmov<DPP_SWAP>(v0), t1 = dppmov<DPP_SWAP>(v1);
                float t2 = dppmov<DPP_SWAP>(v2), t3 = dppmov<DPP_SWAP>(v3);
                unsigned u0 = pkrtz(odd ? t2 : v0, odd ? v2 : t0);
                unsigned u1 = pkrtz(odd ? t3 : v1, odd ? v3 : t1);
                int rowA = 16 * mt + 4 * q + (odd ? 2 : 0);
                int c    = 2 * nt + (n >> 3);
                int a0   = (rowA * 8 + (c ^ ((rowA >> 1) & 7))) * 4 + ((n >> 1) & 3);
                sl[a0] = u0; sl[a0 + 32] = u1;
            }
        }

        // ---- layer 2: slab0 -> slab1 ----
#pragma unroll
        for (int mt = 0; mt < 2; mt++) {
            const int M0 = 16 * mt;
            f32x4 acc[4];
#pragma unroll
            for (int nt = 0; nt < 4; nt++) { f32x4 c; c[0]=c[1]=c[2]=c[3]=bb2[nt]; acc[nt]=c; }
#pragma unroll
            for (int s = 0; s < 2; s++) {
                half8 a = *(const half8*)(slab0 + ((M0 + n) * 8 + ((s * 4 + q) ^ swr)) * 16);
#pragma unroll
                for (int nt = 0; nt < 4; nt++)
                    acc[nt] = __builtin_amdgcn_mfma_f32_16x16x32_f16(a, bw2[nt][s], acc[nt], 0, 0, 0);
            }
            unsigned* sl = (unsigned*)slab1;
#pragma unroll
            for (int nt = 0; nt < 4; nt++) {
                float v0 = fmaxf(acc[nt][0], 0.0f), v1 = fmaxf(acc[nt][1], 0.0f);
                float v2 = fmaxf(acc[nt][2], 0.0f), v3 = fmaxf(acc[nt][3], 0.0f);
                float t0 = dppmov<DPP_SWAP>(v0), t1 = dppmov<DPP_SWAP>(v1);
                float t2 = dppmov<DPP_SWAP>(v2), t3 = dppmov<DPP_SWAP>(v3);
                unsigned u0 = pkrtz(odd ? t2 : v0, odd ? v2 : t0);
                unsigned u1 = pkrtz(odd ? t3 : v1, odd ? v3 : t1);
                int rowA = M0 + 4 * q + (odd ? 2 : 0);
                int c    = 2 * nt + (n >> 3);
                int a0   = (rowA * 8 + (c ^ ((rowA >> 1) & 7))) * 4 + ((n >> 1) & 3);
                sl[a0] = u0; sl[a0 + 32] = u1;
            }
        }

        // ---- layer 3 + 4: slab1 -> scores (DPP row_ror reduce over 16 lanes) ----
#pragma unroll
        for (int mt = 0; mt < 2; mt++) {
            const int M0 = 16 * mt;
            f32x4 acc[2];
#pragma unroll
            for (int nt = 0; nt < 2; nt++) { f32x4 c; c[0]=c[1]=c[2]=c[3]=bb3[nt]; acc[nt]=c; }
#pragma unroll
            for (int s = 0; s < 2; s++) {
                half8 a = *(const half8*)(slab1 + ((M0 + n) * 8 + ((s * 4 + q) ^ swr)) * 16);
#pragma unroll
                for (int nt = 0; nt < 2; nt++)
                    acc[nt] = __builtin_amdgcn_mfma_f32_16x16x32_f16(a, bw3[nt][s], acc[nt], 0, 0, 0);
            }
            f32x4 red;
#pragma unroll
            for (int r = 0; r < 4; r++)
                red[r] = fmaxf(acc[0][r], 0.0f) * w4a + fmaxf(acc[1][r], 0.0f) * w4b;
#pragma unroll
            for (int r = 0; r < 4; r++) {
                red[r] += dppmov<0x121>(red[r]);   // row_ror:1
                red[r] += dppmov<0x122>(red[r]);   // row_ror:2
                red[r] += dppmov<0x124>(red[r]);   // row_ror:4
                red[r] += dppmov<0x128>(red[r]);   // row_ror:8
            }
            int t = rowbase + M0 + q * 4 + n;      // n<4 selects reg n
            float val = (n == 0) ? red[0] : (n == 1) ? red[1] : (n == 2) ? red[2] : red[3];
            if (n < 4 && t < T) out[t] = val + b4v;
        }
    }
}

extern "C" void kernel_launch(void* const* d_in, const int* in_sizes, int n_in,
                              void* d_out, int out_size, void* d_ws, size_t ws_size,
                              hipStream_t stream)
{
    const float* x             = (const float*)d_in[0];
    const float* h_dag         = (const float*)d_in[1];
    const float* h_glob        = (const float*)d_in[2];
    const int*   ptr           = (const int*)d_in[3];
    const int*   job_indices   = (const int*)d_in[4];
    const int*   num_exec_acts = (const int*)d_in[5];
    const int*   exec_act_idx  = (const int*)d_in[6];
    const float* W1 = (const float*)d_in[7];
    const float* b1 = (const float*)d_in[8];
    const float* W2 = (const float*)d_in[9];
    const float* b2 = (const float*)d_in[10];
    const float* W3 = (const float*)d_in[11];
    const float* b3 = (const float*)d_in[12];
    const float* W4 = (const float*)d_in[13];
    const float* b4 = (const float*)d_in[14];
    float* out = (float*)d_out;

    int J  = in_sizes[4];
    int T  = in_sizes[6];
    int nb = (J + TPB - 1) / TPB;

    // workspace layout
    char* wsp = (char*)d_ws;
    int* rpt = (int*)wsp;
    wsp += (((size_t)T * 4) + 255) / 256 * 256;
    int* bsum = (int*)wsp;
    wsp += (((size_t)nb * 4) + 255) / 256 * 256;
    int* boff = (int*)wsp;
    wsp += (((size_t)nb * 4) + 255) / 256 * 256;
    unsigned int* feat = (unsigned int*)wsp;   // J*20 words

    k_prep<<<nb, TPB, 0, stream>>>(x, h_dag, h_glob, ptr, job_indices, num_exec_acts, J, feat, bsum);
    k_scan_bsums<<<1, TPB, 0, stream>>>(bsum, nb, boff);
    k_starts_fill<<<nb, TPB, 0, stream>>>(job_indices, num_exec_acts, boff, J, rpt);

    int numTiles = (T + 127) / 128;
    int grid = numTiles < 1024 ? numTiles : 1024;
    k_mlp_mfma<<<grid, TPB, 0, stream>>>(feat, rpt, exec_act_idx,
                                         W1, b1, W2, b2, W3, b3, W4, b4, out, T, numTiles);
}

// Round 7
// 181.033 us; speedup vs baseline: 2.3888x; 1.0163x over previous
//
#include <hip/hip_runtime.h>

#define TPB 256

using half8  = __attribute__((ext_vector_type(8))) _Float16;
using fp16x2 = __attribute__((ext_vector_type(2))) __fp16;
using f32x4  = __attribute__((ext_vector_type(4))) float;

static __device__ __forceinline__ unsigned short h2u(_Float16 h) {
    union { _Float16 h; unsigned short u; } v; v.h = h; return v.u;
}
static __device__ __forceinline__ unsigned pkrtz(float a, float b) {
    fp16x2 h = __builtin_amdgcn_cvt_pkrtz(a, b);
    return __builtin_bit_cast(unsigned, h);
}
template <int CTRL>
static __device__ __forceinline__ float dppmov(float x) {
    return __int_as_float(__builtin_amdgcn_mov_dpp(__float_as_int(x), CTRL, 0xF, 0xF, true));
}
#define DPP_SWAP 0xB1   // quad_perm [1,0,3,2]

// ---------- kernel 1: pack fp16 features + local scan; emit (excl_start<<6|v) and block sum ----------
__global__ __launch_bounds__(TPB) void k_prep(const float* __restrict__ x,
                                              const float* __restrict__ h_dag,
                                              const float* __restrict__ h_glob,
                                              const int* __restrict__ ptr,
                                              const int* __restrict__ job_indices,
                                              const int* __restrict__ num_exec_acts,
                                              int J, unsigned int* __restrict__ feat,
                                              int* __restrict__ bsum, int* __restrict__ jsv)
{
    __shared__ int sc[TPB];
    int j = blockIdx.x * TPB + threadIdx.x;
    int v = 0;
    if (j < J) {
        int ji   = job_indices[j];
        v        = num_exec_acts[ji];
        int node = ptr[ji];
        float f[40];
        f[0] = x[node * 5 + 0];
        f[1] = x[node * 5 + 1];
        f[2] = x[node * 5 + 2];
#pragma unroll
        for (int c = 0; c < 16; c++) f[3 + c]  = h_dag[ji * 16 + c];
#pragma unroll
        for (int c = 0; c < 16; c++) f[19 + c] = h_glob[j * 16 + c];
#pragma unroll
        for (int c = 35; c < 40; c++) f[c] = 0.0f;
        unsigned int w[20];
#pragma unroll
        for (int k = 0; k < 20; k++)
            w[k] = (unsigned)h2u((_Float16)f[2 * k]) | ((unsigned)h2u((_Float16)f[2 * k + 1]) << 16);
        uint4* dst = (uint4*)(feat + (size_t)j * 20);
#pragma unroll
        for (int qq = 0; qq < 5; qq++)
            dst[qq] = make_uint4(w[4 * qq], w[4 * qq + 1], w[4 * qq + 2], w[4 * qq + 3]);
    }
    // inclusive scan of v
    sc[threadIdx.x] = v;
    __syncthreads();
    for (int d = 1; d < TPB; d <<= 1) {
        int add = (threadIdx.x >= d) ? sc[threadIdx.x - d] : 0;
        __syncthreads();
        sc[threadIdx.x] += add;
        __syncthreads();
    }
    if (j < J) jsv[j] = ((sc[threadIdx.x] - v) << 6) | v;
    if (threadIdx.x == TPB - 1) bsum[blockIdx.x] = sc[TPB - 1];
}

// ---------- kernel 2 (1 block): scan block sums AND build weight/bias fragment buffers ----------
__global__ __launch_bounds__(TPB) void k_scan_wprep(const int* __restrict__ bsum, int nb,
                                                    int* __restrict__ boff,
                                                    const float* __restrict__ W1,
                                                    const float* __restrict__ b1,
                                                    const float* __restrict__ W2,
                                                    const float* __restrict__ b2,
                                                    const float* __restrict__ W3,
                                                    const float* __restrict__ b3,
                                                    const float* __restrict__ W4,
                                                    uint4* __restrict__ wfrag,
                                                    float4* __restrict__ bfrag)
{
    __shared__ int sc[TPB];
    int v = (threadIdx.x < nb) ? bsum[threadIdx.x] : 0;
    sc[threadIdx.x] = v;
    __syncthreads();
    for (int d = 1; d < TPB; d <<= 1) {
        int add = (threadIdx.x >= d) ? sc[threadIdx.x - d] : 0;
        __syncthreads();
        sc[threadIdx.x] += add;
        __syncthreads();
    }
    if (threadIdx.x < nb) boff[threadIdx.x] = sc[threadIdx.x] - v;  // exclusive

    // weight fragments: lane = threadIdx.x (0..63), n = lane&15, q = lane>>4
    if (threadIdx.x < 64) {
        int lane = threadIdx.x;
        int n = lane & 15, q = lane >> 4;
#pragma unroll
        for (int nt = 0; nt < 4; nt++) {
#pragma unroll
            for (int s = 0; s < 2; s++) {
                half8 w1f, w2f;
#pragma unroll
                for (int jj = 0; jj < 8; jj++) {
                    int ks = s * 32 + q * 8 + jj;
                    w1f[jj] = (ks < 36) ? (_Float16)W1[ks * 64 + nt * 16 + n] : (_Float16)0.0f;
                    w2f[jj] = (_Float16)W2[ks * 64 + nt * 16 + n];
                }
                wfrag[(nt * 2 + s) * 64 + lane]     = __builtin_bit_cast(uint4, w1f);
                wfrag[(8 + nt * 2 + s) * 64 + lane] = __builtin_bit_cast(uint4, w2f);
            }
        }
#pragma unroll
        for (int nt = 0; nt < 2; nt++) {
#pragma unroll
            for (int s = 0; s < 2; s++) {
                half8 w3f;
#pragma unroll
                for (int jj = 0; jj < 8; jj++) {
                    int ks = s * 32 + q * 8 + jj;
                    w3f[jj] = (_Float16)W3[ks * 32 + nt * 16 + n];
                }
                wfrag[(16 + nt * 2 + s) * 64 + lane] = __builtin_bit_cast(uint4, w3f);
            }
        }
        bfrag[0 * 64 + lane] = make_float4(b1[n], b1[16 + n], b1[32 + n], b1[48 + n]);
        bfrag[1 * 64 + lane] = make_float4(b2[n], b2[16 + n], b2[32 + n], b2[48 + n]);
        bfrag[2 * 64 + lane] = make_float4(b3[n], b3[16 + n], W4[n], W4[16 + n]);
    }
}

// ---------- kernel 3: trivial rpt fill from packed jsv ----------
__global__ __launch_bounds__(TPB) void k_fill(const int* __restrict__ jsv,
                                              const int* __restrict__ boff,
                                              int J, int* __restrict__ rpt)
{
    int j = blockIdx.x * TPB + threadIdx.x;
    if (j >= J) return;
    int pv    = jsv[j];
    int v     = pv & 63;
    int start = boff[blockIdx.x] + (pv >> 6);
    for (int k = 0; k < v; k++) rpt[start + k] = j;
}

// ---------- kernel 4: fused MFMA MLP, wave-private 32-row tiles ----------
__global__ __launch_bounds__(TPB) void k_mlp_mfma(const unsigned int* __restrict__ feat,
                                                  const int* __restrict__ rpt,
                                                  const int* __restrict__ exec_act_idx,
                                                  const uint4* __restrict__ wfrag,
                                                  const float4* __restrict__ bfrag,
                                                  const float* __restrict__ b4,
                                                  float* __restrict__ out, int T, int numTiles)
{
    __shared__ __align__(16) char smem[4 * 8192];
    const int tid  = threadIdx.x;
    const int lane = tid & 63;
    const int wv   = tid >> 6;
    const int n    = lane & 15;
    const int q    = lane >> 4;
    char* slab0 = smem + wv * 8192;        // A2
    char* slab1 = slab0 + 4096;            // A3

    // ---- fragment loads: 23 coalesced 16B loads ----
    half8 bw1[4][2], bw2[4][2], bw3[2][2];
#pragma unroll
    for (int nt = 0; nt < 4; nt++)
#pragma unroll
        for (int s = 0; s < 2; s++) {
            bw1[nt][s] = __builtin_bit_cast(half8, wfrag[(nt * 2 + s) * 64 + lane]);
            bw2[nt][s] = __builtin_bit_cast(half8, wfrag[(8 + nt * 2 + s) * 64 + lane]);
        }
#pragma unroll
    for (int nt = 0; nt < 2; nt++)
#pragma unroll
        for (int s = 0; s < 2; s++)
            bw3[nt][s] = __builtin_bit_cast(half8, wfrag[(16 + nt * 2 + s) * 64 + lane]);

    float4 bf1 = bfrag[0 * 64 + lane];
    float4 bf2 = bfrag[1 * 64 + lane];
    float4 bf3 = bfrag[2 * 64 + lane];
    float bb1[4] = {bf1.x, bf1.y, bf1.z, bf1.w};
    float bb2[4] = {bf2.x, bf2.y, bf2.z, bf2.w};
    float bb3[2] = {bf3.x, bf3.y};
    const float w4a = bf3.z, w4b = bf3.w;
    const float b4v = b4[0];
    const int   swr = (n >> 1) & 7;
    const int   odd = n & 1;

    for (int tile = blockIdx.x; tile < numTiles; tile += gridDim.x) {
        const int rowbase = tile * 128 + wv * 32;

        // ---- A1 fragments straight from global ----
        half8 a1[2][2];
#pragma unroll
        for (int mt = 0; mt < 2; mt++) {
            int  rt    = rowbase + 16 * mt + n;
            bool valid = rt < T;
            int  j     = valid ? rpt[rt] : 0;
            const uint4* fsrc = (const uint4*)(feat + (size_t)j * 20);
            uint4 g0 = fsrc[q];
            a1[mt][0] = __builtin_bit_cast(half8, g0);
            uint4 g1 = make_uint4(0, 0, 0, 0);
            if (q == 0) {
                g1 = fsrc[4];
                float fe = valid ? (float)exec_act_idx[rt] * 0.02f : 0.0f;
                g1.y = (g1.y & 0xffffu) | ((unsigned)h2u((_Float16)fe) << 16);
            }
            a1[mt][1] = __builtin_bit_cast(half8, g1);
        }

        // ---- layer 1 -> slab0 ----
#pragma unroll
        for (int mt = 0; mt < 2; mt++) {
            f32x4 acc[4];
#pragma unroll
            for (int nt = 0; nt < 4; nt++) { f32x4 c; c[0]=c[1]=c[2]=c[3]=bb1[nt]; acc[nt]=c; }
#pragma unroll
            for (int s = 0; s < 2; s++) {
#pragma unroll
                for (int nt = 0; nt < 4; nt++)
                    acc[nt] = __builtin_amdgcn_mfma_f32_16x16x32_f16(a1[mt][s], bw1[nt][s], acc[nt], 0, 0, 0);
            }
            unsigned* sl = (unsigned*)slab0;
#pragma unroll
            for (int nt = 0; nt < 4; nt++) {
                float v0 = fmaxf(acc[nt][0], 0.0f), v1 = fmaxf(acc[nt][1], 0.0f);
                float v2 = fmaxf(acc[nt][2], 0.0f), v3 = fmaxf(acc[nt][3], 0.0f);
                float t0 = dppmov<DPP_SWAP>(v0), t1 = dppmov<DPP_SWAP>(v1);
                float t2 = dppmov<DPP_SWAP>(v2), t3 = dppmov<DPP_SWAP>(v3);
                unsigned u0 = pkrtz(odd ? t2 : v0, odd ? v2 : t0);
                unsigned u1 = pkrtz(odd ? t3 : v1, odd ? v3 : t1);
                int rowA = 16 * mt + 4 * q + (odd ? 2 : 0);
                int c    = 2 * nt + (n >> 3);
                int a0   = (rowA * 8 + (c ^ ((rowA >> 1) & 7))) * 4 + ((n >> 1) & 3);
                sl[a0] = u0; sl[a0 + 32] = u1;
            }
        }

        // ---- layer 2: slab0 -> slab1 ----
#pragma unroll
        for (int mt = 0; mt < 2; mt++) {
            const int M0 = 16 * mt;
            f32x4 acc[4];
#pragma unroll
            for (int nt = 0; nt < 4; nt++) { f32x4 c; c[0]=c[1]=c[2]=c[3]=bb2[nt]; acc[nt]=c; }
#pragma unroll
            for (int s = 0; s < 2; s++) {
                half8 a = *(const half8*)(slab0 + ((M0 + n) * 8 + ((s * 4 + q) ^ swr)) * 16);
#pragma unroll
                for (int nt = 0; nt < 4; nt++)
                    acc[nt] = __builtin_amdgcn_mfma_f32_16x16x32_f16(a, bw2[nt][s], acc[nt], 0, 0, 0);
            }
            unsigned* sl = (unsigned*)slab1;
#pragma unroll
            for (int nt = 0; nt < 4; nt++) {
                float v0 = fmaxf(acc[nt][0], 0.0f), v1 = fmaxf(acc[nt][1], 0.0f);
                float v2 = fmaxf(acc[nt][2], 0.0f), v3 = fmaxf(acc[nt][3], 0.0f);
                float t0 = dppmov<DPP_SWAP>(v0), t1 = dppmov<DPP_SWAP>(v1);
                float t2 = dppmov<DPP_SWAP>(v2), t3 = dppmov<DPP_SWAP>(v3);
                unsigned u0 = pkrtz(odd ? t2 : v0, odd ? v2 : t0);
                unsigned u1 = pkrtz(odd ? t3 : v1, odd ? v3 : t1);
                int rowA = M0 + 4 * q + (odd ? 2 : 0);
                int c    = 2 * nt + (n >> 3);
                int a0   = (rowA * 8 + (c ^ ((rowA >> 1) & 7))) * 4 + ((n >> 1) & 3);
                sl[a0] = u0; sl[a0 + 32] = u1;
            }
        }

        // ---- layer 3 + 4: slab1 -> scores ----
#pragma unroll
        for (int mt = 0; mt < 2; mt++) {
            const int M0 = 16 * mt;
            f32x4 acc[2];
#pragma unroll
            for (int nt = 0; nt < 2; nt++) { f32x4 c; c[0]=c[1]=c[2]=c[3]=bb3[nt]; acc[nt]=c; }
#pragma unroll
            for (int s = 0; s < 2; s++) {
                half8 a = *(const half8*)(slab1 + ((M0 + n) * 8 + ((s * 4 + q) ^ swr)) * 16);
#pragma unroll
                for (int nt = 0; nt < 2; nt++)
                    acc[nt] = __builtin_amdgcn_mfma_f32_16x16x32_f16(a, bw3[nt][s], acc[nt], 0, 0, 0);
            }
            f32x4 red;
#pragma unroll
            for (int r = 0; r < 4; r++)
                red[r] = fmaxf(acc[0][r], 0.0f) * w4a + fmaxf(acc[1][r], 0.0f) * w4b;
#pragma unroll
            for (int r = 0; r < 4; r++) {
                red[r] += dppmov<0x121>(red[r]);   // row_ror:1
                red[r] += dppmov<0x122>(red[r]);   // row_ror:2
                red[r] += dppmov<0x124>(red[r]);   // row_ror:4
                red[r] += dppmov<0x128>(red[r]);   // row_ror:8
            }
            int t = rowbase + M0 + q * 4 + n;
            float val = (n == 0) ? red[0] : (n == 1) ? red[1] : (n == 2) ? red[2] : red[3];
            if (n < 4 && t < T) out[t] = val + b4v;
        }
    }
}

extern "C" void kernel_launch(void* const* d_in, const int* in_sizes, int n_in,
                              void* d_out, int out_size, void* d_ws, size_t ws_size,
                              hipStream_t stream)
{
    const float* x             = (const float*)d_in[0];
    const float* h_dag         = (const float*)d_in[1];
    const float* h_glob        = (const float*)d_in[2];
    const int*   ptr           = (const int*)d_in[3];
    const int*   job_indices   = (const int*)d_in[4];
    const int*   num_exec_acts = (const int*)d_in[5];
    const int*   exec_act_idx  = (const int*)d_in[6];
    const float* W1 = (const float*)d_in[7];
    const float* b1 = (const float*)d_in[8];
    const float* W2 = (const float*)d_in[9];
    const float* b2 = (const float*)d_in[10];
    const float* W3 = (const float*)d_in[11];
    const float* b3 = (const float*)d_in[12];
    const float* W4 = (const float*)d_in[13];
    const float* b4 = (const float*)d_in[14];
    float* out = (float*)d_out;

    int J  = in_sizes[4];
    int T  = in_sizes[6];
    int nb = (J + TPB - 1) / TPB;

    // workspace layout
    char* wsp = (char*)d_ws;
    int* rpt = (int*)wsp;
    wsp += (((size_t)T * 4) + 255) / 256 * 256;
    int* bsum = (int*)wsp;
    wsp += (((size_t)nb * 4) + 255) / 256 * 256;
    int* boff = (int*)wsp;
    wsp += (((size_t)nb * 4) + 255) / 256 * 256;
    int* jsv = (int*)wsp;
    wsp += (((size_t)J * 4) + 255) / 256 * 256;
    uint4* wfrag = (uint4*)wsp;            // 20*64*16 B
    wsp += 20 * 64 * 16;
    float4* bfrag = (float4*)wsp;          // 3*64*16 B
    wsp += 3 * 64 * 16;
    unsigned int* feat = (unsigned int*)wsp;   // J*20 words

    k_prep<<<nb, TPB, 0, stream>>>(x, h_dag, h_glob, ptr, job_indices, num_exec_acts,
                                   J, feat, bsum, jsv);
    k_scan_wprep<<<1, TPB, 0, stream>>>(bsum, nb, boff, W1, b1, W2, b2, W3, b3, W4,
                                        wfrag, bfrag);
    k_fill<<<nb, TPB, 0, stream>>>(jsv, boff, J, rpt);

    int numTiles = (T + 127) / 128;
    int grid = numTiles < 1024 ? numTiles : 1024;
    k_mlp_mfma<<<grid, TPB, 0, stream>>>(feat, rpt, exec_act_idx, wfrag, bfrag, b4,
                                         out, T, numTiles);
}